// Round 5
// baseline (194.105 us; speedup 1.0000x reference)
//
#include <hip/hip_runtime.h>
#include <hip/hip_bf16.h>
#include <cstddef>
#include <cstdint>

#define Bb 4
#define Tt 1024
#define Dd 1024
#define Hh 16

typedef __bf16 bf16x8 __attribute__((ext_vector_type(8)));
typedef __bf16 bf16x4 __attribute__((ext_vector_type(4)));
typedef float  f32x4  __attribute__((ext_vector_type(4)));

__device__ __forceinline__ void gload16(const void* g, void* l) {
    __builtin_amdgcn_global_load_lds(
        (const __attribute__((address_space(1))) void*)g,
        (__attribute__((address_space(3))) void*)l, 16, 0, 0);
}

// ---------------------------------------------------------------------------
// Fused prep: [0,4096) cast x -> bf16; [4096,4864) Wqkv transpose;
// [4864,5120) Wproj transpose. One launch instead of three.
// ---------------------------------------------------------------------------
__global__ __launch_bounds__(256) void prep(const float* __restrict__ x,
                                            const float* __restrict__ Wqkv,
                                            const float* __restrict__ Wproj,
                                            __bf16* __restrict__ xb,
                                            __bf16* __restrict__ wqT,
                                            __bf16* __restrict__ wpT) {
    const int bid = blockIdx.x;
    if (bid < 4096) {  // cast
        int i = bid * 256 + threadIdx.x;
        float4 v = ((const float4*)x)[i];
        bf16x4 o = { (__bf16)v.x, (__bf16)v.y, (__bf16)v.z, (__bf16)v.w };
        ((bf16x4*)xb)[i] = o;
        return;
    }
    // transpose_cast: W[K][N] fp32 -> W^T[N][K] bf16
    __shared__ float ld[64][65];
    const float* in;
    __bf16* out;
    int K, N, k0, n0;
    if (bid < 4096 + 768) {
        int j = bid - 4096;
        in = Wqkv; out = wqT; K = 1024; N = 3072;
        k0 = (j & 15) * 64; n0 = (j >> 4) * 64;
    } else {
        int j = bid - 4096 - 768;
        in = Wproj; out = wpT; K = 1024; N = 1024;
        k0 = (j & 15) * 64; n0 = (j >> 4) * 64;
    }
    #pragma unroll
    for (int i = 0; i < 16; i++) {
        int idx = i * 256 + threadIdx.x;
        int r = idx >> 6, c = idx & 63;
        ld[r][c] = in[(size_t)(k0 + r) * N + n0 + c];
    }
    __syncthreads();
    #pragma unroll
    for (int i = 0; i < 16; i++) {
        int idx = i * 256 + threadIdx.x;
        int r = idx >> 6, c = idx & 63;
        out[(size_t)(n0 + r) * K + k0 + c] = (__bf16)ld[c][r];
    }
}

// ---------------------------------------------------------------------------
// V slice of qkv [b][t][3072] (cols 2048 + h*64 + d) -> vt [b][h][d][t] bf16
// ---------------------------------------------------------------------------
__global__ __launch_bounds__(256) void v_transpose(const __bf16* __restrict__ qkv,
                                                   __bf16* __restrict__ vt) {
    __shared__ __bf16 ld[64][65];
    const int t0 = blockIdx.x * 64;
    const int h  = blockIdx.y;
    const int b  = blockIdx.z;
    const size_t src = ((size_t)(b * Tt + t0)) * 3072 + 2048 + h * 64;
    #pragma unroll
    for (int i = 0; i < 16; i++) {
        int idx = i * 256 + threadIdx.x;
        int tr = idx >> 6, dc = idx & 63;
        ld[tr][dc] = qkv[src + (size_t)tr * 3072 + dc];
    }
    __syncthreads();
    const size_t dst = ((size_t)((b * Hh + h) * 64)) * Tt + t0;
    #pragma unroll
    for (int i = 0; i < 16; i++) {
        int idx = i * 256 + threadIdx.x;
        int dr = idx >> 6, tc = idx & 63;
        vt[dst + (size_t)dr * Tt + tc] = ld[tc][dr];
    }
}

// ---------------------------------------------------------------------------
// 128x128 MFMA GEMM, BK=64, XOR-8 swizzled LDS. C = A @ Bt^T + bias.
// mode 0: fp32 out. mode 1 (qkv): bf16 out, cols<1024 scaled by 0.125.
// ---------------------------------------------------------------------------
__global__ __launch_bounds__(256) void gemm_bf16(const __bf16* __restrict__ A,
                                                 const __bf16* __restrict__ Bt,
                                                 const float* __restrict__ bias,
                                                 void* __restrict__ Cout,
                                                 int M, int N, int K, int mode) {
    __shared__ __align__(16) __bf16 As[128 * 64];
    __shared__ __align__(16) __bf16 Bs[128 * 64];
    const int tid  = threadIdx.x;
    const int lane = tid & 63;
    const int wave = tid >> 6;
    const int wy = wave >> 1, wx = wave & 1;
    const int l15 = lane & 15, quad = lane >> 4;
    const size_t row0 = (size_t)blockIdx.y * 128;
    const size_t col0 = (size_t)blockIdx.x * 128;

    f32x4 acc[4][4] = {};

    for (int k0 = 0; k0 < K; k0 += 64) {
        #pragma unroll
        for (int i = 0; i < 4; i++) {
            int c = i * 256 + tid;
            int r = c >> 3, seg = (c & 7) ^ (r & 7);
            gload16(&A[(row0 + r) * K + k0 + seg * 8], &As[c * 8]);
        }
        #pragma unroll
        for (int i = 0; i < 4; i++) {
            int c = i * 256 + tid;
            int r = c >> 3, seg = (c & 7) ^ (r & 7);
            gload16(&Bt[(col0 + r) * K + k0 + seg * 8], &Bs[c * 8]);
        }
        __syncthreads();
        #pragma unroll
        for (int kc = 0; kc < 2; kc++) {
            bf16x8 af[4], bfr[4];
            #pragma unroll
            for (int i = 0; i < 4; i++)
                af[i] = *(const bf16x8*)&As[(wy * 64 + i * 16 + l15) * 64 +
                                            (((kc * 4 + quad) ^ (l15 & 7)) * 8)];
            #pragma unroll
            for (int j = 0; j < 4; j++)
                bfr[j] = *(const bf16x8*)&Bs[(wx * 64 + j * 16 + l15) * 64 +
                                             (((kc * 4 + quad) ^ (l15 & 7)) * 8)];
            #pragma unroll
            for (int i = 0; i < 4; i++)
                #pragma unroll
                for (int j = 0; j < 4; j++)
                    acc[i][j] = __builtin_amdgcn_mfma_f32_16x16x32_bf16(af[i], bfr[j], acc[i][j], 0, 0, 0);
        }
        __syncthreads();
    }

    #pragma unroll
    for (int j = 0; j < 4; j++) {
        const size_t col = col0 + wx * 64 + j * 16 + l15;
        const float bj = bias[col];
        const float scale = (mode == 1 && col < 1024) ? 0.125f : 1.0f;
        #pragma unroll
        for (int i = 0; i < 4; i++) {
            const size_t row = row0 + wy * 64 + i * 16 + quad * 4;
            #pragma unroll
            for (int r = 0; r < 4; r++) {
                float v = (acc[i][j][r] + bj) * scale;
                if (mode == 1) ((__bf16*)Cout)[(row + r) * N + col] = (__bf16)v;
                else           ((float*)Cout)[(row + r) * N + col] = v;
            }
        }
    }
}

// ---------------------------------------------------------------------------
// 128x64-tile GEMM (proj), BK=64, swizzled. fp32 out.
// ---------------------------------------------------------------------------
__global__ __launch_bounds__(256) void gemm_bf16_n64(const __bf16* __restrict__ A,
                                                     const __bf16* __restrict__ Bt,
                                                     const float* __restrict__ bias,
                                                     float* __restrict__ Cout,
                                                     int M, int N, int K) {
    __shared__ __align__(16) __bf16 As[128 * 64];
    __shared__ __align__(16) __bf16 Bs[64 * 64];
    const int tid  = threadIdx.x;
    const int lane = tid & 63;
    const int wave = tid >> 6;
    const int wy = wave >> 1, wx = wave & 1;
    const int l15 = lane & 15, quad = lane >> 4;
    const size_t row0 = (size_t)blockIdx.y * 128;
    const size_t col0 = (size_t)blockIdx.x * 64;

    f32x4 acc[4][2] = {};

    for (int k0 = 0; k0 < K; k0 += 64) {
        #pragma unroll
        for (int i = 0; i < 4; i++) {
            int c = i * 256 + tid;
            int r = c >> 3, seg = (c & 7) ^ (r & 7);
            gload16(&A[(row0 + r) * K + k0 + seg * 8], &As[c * 8]);
        }
        #pragma unroll
        for (int i = 0; i < 2; i++) {
            int c = i * 256 + tid;
            int r = c >> 3, seg = (c & 7) ^ (r & 7);
            gload16(&Bt[(col0 + r) * K + k0 + seg * 8], &Bs[c * 8]);
        }
        __syncthreads();
        #pragma unroll
        for (int kc = 0; kc < 2; kc++) {
            bf16x8 af[4], bfr[2];
            #pragma unroll
            for (int i = 0; i < 4; i++)
                af[i] = *(const bf16x8*)&As[(wy * 64 + i * 16 + l15) * 64 +
                                            (((kc * 4 + quad) ^ (l15 & 7)) * 8)];
            #pragma unroll
            for (int j = 0; j < 2; j++)
                bfr[j] = *(const bf16x8*)&Bs[(wx * 32 + j * 16 + l15) * 64 +
                                             (((kc * 4 + quad) ^ (l15 & 7)) * 8)];
            #pragma unroll
            for (int i = 0; i < 4; i++)
                #pragma unroll
                for (int j = 0; j < 2; j++)
                    acc[i][j] = __builtin_amdgcn_mfma_f32_16x16x32_bf16(af[i], bfr[j], acc[i][j], 0, 0, 0);
        }
        __syncthreads();
    }

    #pragma unroll
    for (int j = 0; j < 2; j++) {
        const size_t col = col0 + wx * 32 + j * 16 + l15;
        const float bj = bias[col];
        #pragma unroll
        for (int i = 0; i < 4; i++) {
            const size_t row = row0 + wy * 64 + i * 16 + quad * 4;
            #pragma unroll
            for (int r = 0; r < 4; r++)
                Cout[(row + r) * N + col] = acc[i][j][r] + bj;
        }
    }
}

// ---------------------------------------------------------------------------
// Flash attention, S^T = K @ Q^T form. Q fragments preloaded to registers
// (loop-invariant) -> Q LDS region reused; K/V single-buffered (24 KB total,
// 3 blocks/CU). Next-iter DMA issued after a frag-reads-done barrier, so it
// overlaps compute. Fold-pair Q tiles (block p: qlo=p, qhi=15-p, 17 strips).
// ---------------------------------------------------------------------------
__global__ __launch_bounds__(256, 3) void attn_mfma(const __bf16* __restrict__ qkv,
                                                    const __bf16* __restrict__ vt,
                                                    const int* __restrict__ mask,
                                                    __bf16* __restrict__ att) {
    // [ Ks 4096 | Vs 4096 | Ps 4096 ] bf16 = 24 KB. Q staged through Ks|Vs.
    __shared__ __align__(16) __bf16 smem[3 * 64 * 64];
    __bf16* const Ks = smem;
    __bf16* const Vs = smem + 4096;
    __bf16* const Ps = smem + 8192;  // per-wave strips of 16*64

    const int p = blockIdx.x, h = blockIdx.y, b = blockIdx.z;
    const int qlo = p, qhi = 15 - p, nk = 16 - p;
    const int tid = threadIdx.x, lane = tid & 63, wave = tid >> 6;
    const int l15 = lane & 15, quad = lane >> 4;

    // ---- stage Q through smem[0..8192), preload frags, then release ----
    #pragma unroll
    for (int i = 0; i < 4; i++) {
        int c = i * 256 + tid;
        int rr = c >> 3, ch = c & 7;
        int w_ = rr >> 5, s_ = (rr >> 4) & 1, r16 = rr & 15;
        int grow = (s_ ? qhi : qlo) * 64 + w_ * 16 + r16;
        gload16(&qkv[((size_t)(b * Tt + grow)) * 3072 + h * 64 + ((ch ^ (rr & 7)) * 8)],
                &smem[c * 8]);
    }
    __syncthreads();
    bf16x8 qf[2][2];
    #pragma unroll
    for (int s = 0; s < 2; s++) {
        const int rowb = wave * 32 + s * 16 + l15;
        qf[s][0] = *(const bf16x8*)&smem[rowb * 64 + ((quad ^ (l15 & 7)) * 8)];
        qf[s][1] = *(const bf16x8*)&smem[rowb * 64 + (((4 + quad) ^ (l15 & 7)) * 8)];
    }
    __syncthreads();  // all Q frag reads done -> region reusable for K/V

    // ---- stage K/V for kt=0 ----
    #pragma unroll
    for (int i = 0; i < 2; i++) {
        int c = i * 256 + tid;
        int rr = c >> 3, ch = c & 7, sw = ((ch ^ (rr & 7)) * 8);
        gload16(&qkv[((size_t)(b * Tt + rr)) * 3072 + 1024 + h * 64 + sw], &Ks[c * 8]);
        gload16(&vt[((size_t)((b * Hh + h) * 64 + rr)) * Tt + sw], &Vs[c * 8]);
    }

    f32x4 Oacc[2][4] = {};
    float lsum[2] = { 0.0f, 0.0f };

    for (int kt = 0; kt < nk; kt++) {
        __syncthreads();  // K/V DMA for kt complete (issued >=1 compute phase ago)

        // preload all K/V fragments for this tile
        bf16x8 ak[4][2], av[4][2];
        #pragma unroll
        for (int j = 0; j < 4; j++)
            #pragma unroll
            for (int kc = 0; kc < 2; kc++) {
                int sw = (((kc * 4 + quad) ^ (l15 & 7)) * 8);
                ak[j][kc] = *(const bf16x8*)&Ks[(j * 16 + l15) * 64 + sw];
                av[j][kc] = *(const bf16x8*)&Vs[(j * 16 + l15) * 64 + sw];
            }
        __syncthreads();  // frag reads done -> tiles safe to overwrite

        if (kt + 1 < nk) {  // next-iter DMA, overlaps compute below
            #pragma unroll
            for (int i = 0; i < 2; i++) {
                int c = i * 256 + tid;
                int rr = c >> 3, ch = c & 7, sw = ((ch ^ (rr & 7)) * 8);
                gload16(&qkv[((size_t)(b * Tt + (kt + 1) * 64 + rr)) * 3072 + 1024 + h * 64 + sw],
                        &Ks[c * 8]);
                gload16(&vt[((size_t)((b * Hh + h) * 64 + rr)) * Tt + (kt + 1) * 64 + sw],
                        &Vs[c * 8]);
            }
        }

        int mv4[4][4];
        #pragma unroll
        for (int j = 0; j < 4; j++) {
            const int4 m4 = *(const int4*)&mask[b * Tt + kt * 64 + j * 16 + quad * 4];
            mv4[j][0] = m4.x; mv4[j][1] = m4.y; mv4[j][2] = m4.z; mv4[j][3] = m4.w;
        }

        #pragma unroll
        for (int s = 1; s >= 0; s--) {
            if (s == 0 && kt > qlo) continue;  // wave-uniform skip
            const int tile = s ? qhi : qlo;
            #pragma unroll
            for (int j = 0; j < 4; j++) {
                f32x4 st = {};
                st = __builtin_amdgcn_mfma_f32_16x16x32_bf16(ak[j][0], qf[s][0], st, 0, 0, 0);
                st = __builtin_amdgcn_mfma_f32_16x16x32_bf16(ak[j][1], qf[s][1], st, 0, 0, 0);
                bf16x4 pv;
                #pragma unroll
                for (int r = 0; r < 4; r++) {
                    const int tloc = j * 16 + quad * 4 + r;
                    bool keep = (mv4[j][r] != 0);
                    if (kt == tile) keep = keep && (tloc <= wave * 16 + l15);
                    const float pe = keep ? __expf(st[r]) : 0.0f;
                    lsum[s] += pe;
                    pv[r] = (__bf16)pe;
                }
                *(bf16x4*)&Ps[wave * 1024 + l15 * 64 + (((j * 4 + quad) ^ ((l15 & 7) << 1)) * 4)] = pv;
            }
            bf16x8 p0 = *(const bf16x8*)&Ps[wave * 1024 + l15 * 64 + (((2 * quad) ^ ((l15 & 7) << 1)) * 4)];
            bf16x8 p1 = *(const bf16x8*)&Ps[wave * 1024 + l15 * 64 + (((2 * (4 + quad)) ^ ((l15 & 7) << 1)) * 4)];
            #pragma unroll
            for (int n = 0; n < 4; n++) {
                Oacc[s][n] = __builtin_amdgcn_mfma_f32_16x16x32_bf16(av[n][0], p0, Oacc[s][n], 0, 0, 0);
                Oacc[s][n] = __builtin_amdgcn_mfma_f32_16x16x32_bf16(av[n][1], p1, Oacc[s][n], 0, 0, 0);
            }
        }
    }

    // epilogue: reduce l across quads, normalize, store (O^T: lane col = q)
    #pragma unroll
    for (int s = 0; s < 2; s++) {
        const int tile = s ? qhi : qlo;
        float lt = lsum[s];
        lt += __shfl_xor(lt, 16);
        lt += __shfl_xor(lt, 32);
        const float inv = 1.0f / lt;
        const int q = tile * 64 + wave * 16 + l15;
        #pragma unroll
        for (int n = 0; n < 4; n++) {
            bf16x4 o;
            #pragma unroll
            for (int r = 0; r < 4; r++) o[r] = (__bf16)(Oacc[s][n][r] * inv);
            *(bf16x4*)&att[((size_t)(b * Tt + q)) * Dd + h * 64 + n * 16 + quad * 4] = o;
        }
    }
}

// ---------------------------------------------------------------------------
extern "C" void kernel_launch(void* const* d_in, const int* in_sizes, int n_in,
                              void* d_out, int out_size, void* d_ws, size_t ws_size,
                              hipStream_t stream) {
    const float* x     = (const float*)d_in[0];
    const float* Wqkv  = (const float*)d_in[1];
    const float* bqkv  = (const float*)d_in[2];
    const float* Wproj = (const float*)d_in[3];
    const float* bproj = (const float*)d_in[4];
    const int*   mask  = (const int*)d_in[5];
    float* out = (float*)d_out;

    __bf16* xb  = (__bf16*)d_ws;                         // 4096*1024
    __bf16* wqT = xb  + (size_t)4096 * 1024;             // 3072*1024
    __bf16* wpT = wqT + (size_t)3072 * 1024;             // 1024*1024
    __bf16* qkv = wpT + (size_t)1024 * 1024;             // 4096*3072
    __bf16* vt  = qkv + (size_t)4096 * 3072;             // 4*16*64*1024
    __bf16* att = vt  + (size_t)4 * 16 * 64 * 1024;      // 4096*1024

    prep<<<4096 + 768 + 256, 256, 0, stream>>>(x, Wqkv, Wproj, xb, wqT, wpT);

    gemm_bf16<<<dim3(24, 32), 256, 0, stream>>>(xb, wqT, bqkv, qkv, 4096, 3072, 1024, 1);

    v_transpose<<<dim3(16, 16, 4), 256, 0, stream>>>(qkv, vt);
    attn_mfma<<<dim3(8, 16, 4), 256, 0, stream>>>(qkv, vt, mask, att);

    gemm_bf16_n64<<<dim3(16, 32), 256, 0, stream>>>(att, wpT, bproj, out, 4096, 1024, 1024);
}